// Round 1
// baseline (130.696 us; speedup 1.0000x reference)
//
#include <hip/hip_runtime.h>
#include <hip/hip_bf16.h>

// DenseEnergyLoss on MI355X.
// N=4, K=21, H=W=128, SCALE=0.5 -> OH=OW=64, P=4096.
// Bilinear resize at exactly 0.5 scale with half-pixel centers == 2x2 average.
// Nearest resize picks even rows/cols (floor(o * 2)).
//
// loss = 0.1 * (-0.5) / (N*P) * sum_{n,p,q} exp(-0.5*max(|f_p|^2+|f_q|^2-2 f_p.f_q,0))
//                                * gate[p] * sum_k seg_m[k,p]*seg_m[k,q]

constexpr int N_ = 4, K_ = 21, H_ = 128, W_ = 128, OH_ = 64, OW_ = 64;
constexpr int P_ = OH_ * OW_;           // 4096
constexpr int REC = 32;                 // floats per (n,p) record
constexpr int QC = 256;                 // q-chunk size staged in LDS
constexpr float INV_RGB = 1.0f / 15.0f; // 1/SIGMA_RGB
constexpr float INV_XY = 1.0f / 40.0f;  // 1/(SIGMA_XY*SCALE)
constexpr float NEG_HALF_LOG2E = -0.72134752044448170f; // -0.5*log2(e)
constexpr float OUT_SCALE = -0.05f / 16384.0f;          // 0.1 * -0.5 / (N*P)

// Record layout (32 floats): [0..20] seg_m[k], [21..23] pad(0),
// [24..28] feat f0..f4, [29] |f|^2, [30] gate, [31] pad.

__global__ void __launch_bounds__(256) prep_kernel(
    const float* __restrict__ img, const float* __restrict__ seg,
    const float* __restrict__ roi, const float* __restrict__ lab,
    float* __restrict__ rec) {
  int idx = blockIdx.x * 256 + threadIdx.x; // n*P + p
  int n = idx >> 12;
  int p = idx & (P_ - 1);
  int y = p >> 6, x = p & 63;
  int iy = 2 * y, ix = 2 * x;
  const size_t hw = (size_t)H_ * W_;

  float r = roi[(size_t)n * hw + iy * W_ + ix];
  float lb = lab[(size_t)n * hw + iy * W_ + ix];
  bool unlabeled = ((int)lb == 255);

  float* out = rec + (size_t)idx * REC;
  const float* sb = seg + (size_t)n * K_ * hw + (size_t)iy * W_ + ix;
  float mx = -1e30f;
#pragma unroll
  for (int k = 0; k < K_; k++) {
    const float* s = sb + (size_t)k * hw;
    float v = 0.25f * (s[0] + s[1] + s[W_] + s[W_ + 1]); // 2x2 avg (bilinear @ 0.5)
    mx = fmaxf(mx, v);
    out[k] = v * r; // seg_m = seg_s * roi
  }
  out[21] = 0.0f; out[22] = 0.0f; out[23] = 0.0f;

  float f0 = (float)x * INV_XY;
  float f1 = (float)y * INV_XY;
  const float* ib = img + (size_t)n * 3 * hw + (size_t)iy * W_ + ix;
  float f2 = ib[0] * INV_RGB;
  float f3 = ib[hw] * INV_RGB;
  float f4 = ib[2 * hw] * INV_RGB;
  out[24] = f0; out[25] = f1; out[26] = f2; out[27] = f3; out[28] = f4;
  out[29] = f0 * f0 + f1 * f1 + f2 * f2 + f3 * f3 + f4 * f4;
  float g = unlabeled ? 1.0f : (r - mx);
  out[30] = fmaxf(g, 0.0f);
  out[31] = 0.0f;
}

__global__ void __launch_bounds__(256) energy_kernel(
    const float* __restrict__ rec, float* __restrict__ out) {
  __shared__ float sh[QC * REC]; // 32 KB

  int pb = blockIdx.y;                 // 0..63 : n*16 + p-block
  int n = pb >> 4;
  int p = (pb & 15) * 256 + threadIdx.x;
  int qc = blockIdx.x;                 // 0..15

  const float* base = rec + (size_t)n * P_ * REC;
  const float* rp = base + (size_t)p * REC;

  float gate = rp[30];
  float t[K_];
#pragma unroll
  for (int k = 0; k < K_; k++) t[k] = rp[k] * gate;
  float f0 = rp[24], f1 = rp[25], f2 = rp[26], f3 = rp[27], f4 = rp[28];
  float sqp = rp[29];

  // Stage q-chunk into LDS (256 records x 128 B).
  const float4* src = (const float4*)(base + (size_t)qc * QC * REC);
  float4* dst = (float4*)sh;
#pragma unroll
  for (int i = 0; i < QC * REC / 4 / 256; i++)
    dst[threadIdx.x + i * 256] = src[threadIdx.x + i * 256];
  __syncthreads();

  float acc = 0.0f;
  for (int q = 0; q < QC; q++) {
    const float* rq = sh + q * REC;
    float dot = f0 * rq[24];
    dot = fmaf(f1, rq[25], dot);
    dot = fmaf(f2, rq[26], dot);
    dot = fmaf(f3, rq[27], dot);
    dot = fmaf(f4, rq[28], dot);
    float d2 = fmaxf(sqp + rq[29] - 2.0f * dot, 0.0f);
    float A = __builtin_amdgcn_exp2f(NEG_HALF_LOG2E * d2);
    float G = 0.0f;
#pragma unroll
    for (int k = 0; k < K_; k++) G = fmaf(t[k], rq[k], G);
    acc = fmaf(A, G, acc);
  }

  // Reduce 256 threads -> 1, then one atomic per block.
#pragma unroll
  for (int off = 32; off > 0; off >>= 1) acc += __shfl_down(acc, off, 64);
  __shared__ float wsum[4];
  int lane = threadIdx.x & 63, wid = threadIdx.x >> 6;
  if (lane == 0) wsum[wid] = acc;
  __syncthreads();
  if (threadIdx.x == 0) {
    float s = (wsum[0] + wsum[1]) + (wsum[2] + wsum[3]);
    atomicAdd(out, s * OUT_SCALE);
  }
}

extern "C" void kernel_launch(void* const* d_in, const int* in_sizes, int n_in,
                              void* d_out, int out_size, void* d_ws, size_t ws_size,
                              hipStream_t stream) {
  const float* images = (const float*)d_in[0];
  const float* segs = (const float*)d_in[1];
  const float* rois = (const float*)d_in[2];
  const float* labels = (const float*)d_in[3];
  float* out = (float*)d_out;
  float* rec = (float*)d_ws; // N*P*REC floats = 2 MB

  hipMemsetAsync(out, 0, sizeof(float), stream);
  prep_kernel<<<dim3(N_ * P_ / 256), dim3(256), 0, stream>>>(images, segs, rois, labels, rec);
  energy_kernel<<<dim3(P_ / QC, N_ * P_ / 256), dim3(256), 0, stream>>>(rec, out);
}

// Round 2
// 110.787 us; speedup vs baseline: 1.1797x; 1.1797x over previous
//
#include <hip/hip_runtime.h>
#include <hip/hip_bf16.h>

// DenseEnergyLoss on MI355X. N=4, K=21, H=W=128 -> OH=OW=64, P=4096.
// loss = 0.1*(-0.5)/(N*P) * sum_{n,p,q} exp(-0.5*max(|f_p-f_q|^2,0)) * gate_p * <seg_p, seg_q>
// Symmetrized: gate_p -> (gate_p+gate_q)/2; upper-triangular 128x128 tiles only
// (diag weight 0.5, off-diag 1.0 after folding the x2).

constexpr int N_ = 4, K_ = 21, H_ = 128, W_ = 128, P_ = 4096;
constexpr int T_ = 128;                  // tile size (p and q)
constexpr int NT = P_ / T_;              // 32 tiles per dim
constexpr int NTRI = NT * (NT + 1) / 2;  // 528 upper-tri tile pairs per n
constexpr int REC = 20;                  // 32-bit words per point record (80 B, 16B-aligned)
constexpr float INV_RGB = 1.0f / 15.0f;
constexpr float INV_XY = 1.0f / 40.0f;   // 1/(SIGMA_XY*SCALE)
constexpr float LOG2E = 1.4426950408889634f;
constexpr float NEG_HALF_LOG2E = -0.72134752044448170f;
constexpr float OUT_SCALE = -0.05f / 16384.0f; // 0.1 * -0.5 / (N*P)

typedef _Float16 half2_t __attribute__((ext_vector_type(2)));

#if __has_builtin(__builtin_amdgcn_fdot2)
#define FDOT2(a, b, c) __builtin_amdgcn_fdot2((a), (b), (c), false)
#else
static __device__ __forceinline__ float FDOT2(half2_t a, half2_t b, float c) {
  return c + (float)a.x * (float)b.x + (float)a.y * (float)b.y;
}
#endif

// Record layout (20 floats): [0..10] seg_m as half2 pairs (k=2j,2j+1; last hi=0),
// [11..15] f0..f4 (f32), [16] cs = -0.5*log2e*|f|^2, [17] gate, [18..19] pad.

__global__ void __launch_bounds__(256) prep_kernel(
    const float* __restrict__ img, const float* __restrict__ seg,
    const float* __restrict__ roi, const float* __restrict__ lab,
    float* __restrict__ rec, float* __restrict__ out) {
  int idx = blockIdx.x * 256 + threadIdx.x; // n*P + p
  if (blockIdx.x == 0 && threadIdx.x == 0) out[0] = 0.0f; // energy runs after prep
  int n = idx >> 12;
  int p = idx & (P_ - 1);
  int y = p >> 6, x = p & 63;
  int iy = 2 * y, ix = 2 * x;
  const size_t hw = (size_t)H_ * W_;

  float r = roi[(size_t)n * hw + iy * W_ + ix];
  float lb = lab[(size_t)n * hw + iy * W_ + ix];
  bool unlabeled = ((int)lb == 255);

  const float* sb = seg + (size_t)n * K_ * hw + (size_t)iy * W_ + ix;
  float sm[22];
  float mx = -1e30f;
#pragma unroll
  for (int k = 0; k < K_; k++) {
    const float* s = sb + (size_t)k * hw;
    float v = 0.25f * (s[0] + s[1] + s[W_] + s[W_ + 1]); // bilinear @0.5 == 2x2 avg
    mx = fmaxf(mx, v);
    sm[k] = v * r; // seg_m = seg_s * roi
  }
  sm[21] = 0.0f;

  float o[REC];
#pragma unroll
  for (int j = 0; j < 11; j++) {
    half2_t h;
    h.x = (_Float16)sm[2 * j];
    h.y = (_Float16)sm[2 * j + 1];
    o[j] = __builtin_bit_cast(float, h);
  }
  float f0 = (float)x * INV_XY;
  float f1 = (float)y * INV_XY;
  const float* ib = img + (size_t)n * 3 * hw + (size_t)iy * W_ + ix;
  float f2 = ib[0] * INV_RGB;
  float f3 = ib[hw] * INV_RGB;
  float f4 = ib[2 * hw] * INV_RGB;
  o[11] = f0; o[12] = f1; o[13] = f2; o[14] = f3; o[15] = f4;
  float sq = f0 * f0;
  sq = fmaf(f1, f1, sq); sq = fmaf(f2, f2, sq);
  sq = fmaf(f3, f3, sq); sq = fmaf(f4, f4, sq);
  o[16] = NEG_HALF_LOG2E * sq;
  float g = unlabeled ? 1.0f : (r - mx);
  o[17] = fmaxf(g, 0.0f);
  o[18] = 0.0f; o[19] = 0.0f;

  float4* dst = (float4*)(rec + (size_t)idx * REC);
  const float4* srcv = (const float4*)o;
#pragma unroll
  for (int j = 0; j < REC / 4; j++) dst[j] = srcv[j];
}

__global__ void __launch_bounds__(64) energy_kernel(
    const float* __restrict__ rec, float* __restrict__ out) {
  __shared__ float sh[T_ * REC]; // 10 KB

  // Decode upper-triangular tile pair (pb <= qb) from blockIdx.x in [0, 528).
  int t = blockIdx.x;
  int pb = 0;
  while (t >= NT - pb) { t -= NT - pb; pb++; }
  int qb = pb + t;
  int n = blockIdx.y;
  int tid = threadIdx.x;

  const float* base = rec + (size_t)n * P_ * REC;

  // Stage q-tile (128 records x 80 B) into LDS.
  const float4* src = (const float4*)(base + (size_t)qb * T_ * REC);
  float4* dst = (float4*)sh;
#pragma unroll
  for (int i = 0; i < T_ * REC / 4 / 64; i++) dst[tid + i * 64] = src[tid + i * 64];

  // Load this thread's two p-records into registers (MP=2).
  half2_t sp[2][11];
  float fp[2][5], csp[2], gp[2];
#pragma unroll
  for (int i = 0; i < 2; i++) {
    const float4* rp4 = (const float4*)(base + (size_t)(pb * T_ + tid + i * 64) * REC);
    float4 b0 = rp4[0], b1 = rp4[1], b2 = rp4[2], b3 = rp4[3], b4 = rp4[4];
    sp[i][0] = __builtin_bit_cast(half2_t, b0.x);
    sp[i][1] = __builtin_bit_cast(half2_t, b0.y);
    sp[i][2] = __builtin_bit_cast(half2_t, b0.z);
    sp[i][3] = __builtin_bit_cast(half2_t, b0.w);
    sp[i][4] = __builtin_bit_cast(half2_t, b1.x);
    sp[i][5] = __builtin_bit_cast(half2_t, b1.y);
    sp[i][6] = __builtin_bit_cast(half2_t, b1.z);
    sp[i][7] = __builtin_bit_cast(half2_t, b1.w);
    sp[i][8] = __builtin_bit_cast(half2_t, b2.x);
    sp[i][9] = __builtin_bit_cast(half2_t, b2.y);
    sp[i][10] = __builtin_bit_cast(half2_t, b2.z);
    fp[i][0] = b2.w;
    fp[i][1] = b3.x; fp[i][2] = b3.y; fp[i][3] = b3.z; fp[i][4] = b3.w;
    csp[i] = b4.x; gp[i] = b4.y;
  }
  __syncthreads();

  float acc = 0.0f;
#pragma unroll 2
  for (int q = 0; q < T_; q++) {
    const float4* rq4 = (const float4*)(sh + q * REC);
    float4 a0 = rq4[0], a1 = rq4[1], a2 = rq4[2], a3 = rq4[3], a4 = rq4[4];
    half2_t q0 = __builtin_bit_cast(half2_t, a0.x);
    half2_t q1 = __builtin_bit_cast(half2_t, a0.y);
    half2_t q2 = __builtin_bit_cast(half2_t, a0.z);
    half2_t q3 = __builtin_bit_cast(half2_t, a0.w);
    half2_t q4 = __builtin_bit_cast(half2_t, a1.x);
    half2_t q5 = __builtin_bit_cast(half2_t, a1.y);
    half2_t q6 = __builtin_bit_cast(half2_t, a1.z);
    half2_t q7 = __builtin_bit_cast(half2_t, a1.w);
    half2_t q8 = __builtin_bit_cast(half2_t, a2.x);
    half2_t q9 = __builtin_bit_cast(half2_t, a2.y);
    half2_t q10 = __builtin_bit_cast(half2_t, a2.z);
    float f0q = a2.w, f1q = a3.x, f2q = a3.y, f3q = a3.z, f4q = a3.w;
    float csq = a4.x, gq = a4.y;
#pragma unroll
    for (int i = 0; i < 2; i++) {
      // K-contraction: 11 half2 dot2s, two accumulators for ILP.
      float Ga = FDOT2(sp[i][0], q0, 0.0f);
      float Gb = FDOT2(sp[i][1], q1, 0.0f);
      Ga = FDOT2(sp[i][2], q2, Ga);
      Gb = FDOT2(sp[i][3], q3, Gb);
      Ga = FDOT2(sp[i][4], q4, Ga);
      Gb = FDOT2(sp[i][5], q5, Gb);
      Ga = FDOT2(sp[i][6], q6, Ga);
      Gb = FDOT2(sp[i][7], q7, Gb);
      Ga = FDOT2(sp[i][8], q8, Ga);
      Gb = FDOT2(sp[i][9], q9, Gb);
      Ga = FDOT2(sp[i][10], q10, Ga);
      // 5-dim feature dot (fp32).
      float dot = fp[i][0] * f0q;
      dot = fmaf(fp[i][1], f1q, dot);
      dot = fmaf(fp[i][2], f2q, dot);
      dot = fmaf(fp[i][3], f3q, dot);
      dot = fmaf(fp[i][4], f4q, dot);
      // A = exp(-0.5*max(d2,0)) = min(exp2(cs_p+cs_q+log2e*dot), 1)
      float arg = fmaf(LOG2E, dot, csp[i] + csq);
      float A = __builtin_amdgcn_exp2f(arg);
      A = fminf(A, 1.0f);
      acc = fmaf(A * (Ga + Gb), gp[i] + gq, acc);
    }
  }

  // Wave reduction (single wave per block) + one atomic.
#pragma unroll
  for (int off = 32; off > 0; off >>= 1) acc += __shfl_down(acc, off, 64);
  if (tid == 0) {
    float wb = (pb == qb) ? 0.5f : 1.0f; // symmetrized-gate 1/2 folded with off-diag x2
    atomicAdd(out, acc * wb * OUT_SCALE);
  }
}

extern "C" void kernel_launch(void* const* d_in, const int* in_sizes, int n_in,
                              void* d_out, int out_size, void* d_ws, size_t ws_size,
                              hipStream_t stream) {
  const float* images = (const float*)d_in[0];
  const float* segs = (const float*)d_in[1];
  const float* rois = (const float*)d_in[2];
  const float* labels = (const float*)d_in[3];
  float* out = (float*)d_out;
  float* rec = (float*)d_ws; // N*P*REC*4 = 1.31 MB

  prep_kernel<<<dim3(N_ * P_ / 256), dim3(256), 0, stream>>>(images, segs, rois, labels, rec, out);
  energy_kernel<<<dim3(NTRI, N_), dim3(64), 0, stream>>>(rec, out);
}

// Round 3
// 103.139 us; speedup vs baseline: 1.2672x; 1.0742x over previous
//
#include <hip/hip_runtime.h>
#include <hip/hip_bf16.h>

// DenseEnergyLoss on MI355X. N=4, K=21, H=W=128 -> OH=OW=64, P=4096.
// loss = 0.1*(-0.5)/(N*P) * sum_{n,p,q} exp(-0.5*max(|f_p-f_q|^2,0)) * gate_p * <seg_p, seg_q>
// Symmetrized: gate_p -> (gate_p+gate_q)/2; upper-triangular 128x128 tiles only
// (diag weight 0.5, off-diag 1.0 after folding the x2).
// R3: 256-thread blocks (4 waves share the LDS q-tile, each wave takes a 32-q
// strip) to raise occupancy 14% -> ~50%+; R2's 1-wave blocks were latency-bound.

constexpr int N_ = 4, K_ = 21, H_ = 128, W_ = 128, P_ = 4096;
constexpr int T_ = 128;                  // tile size (p and q)
constexpr int NT = P_ / T_;              // 32 tiles per dim
constexpr int NTRI = NT * (NT + 1) / 2;  // 528 upper-tri tile pairs per n
constexpr int REC = 20;                  // 32-bit words per point record (80 B)
constexpr float INV_RGB = 1.0f / 15.0f;
constexpr float INV_XY = 1.0f / 40.0f;   // 1/(SIGMA_XY*SCALE)
constexpr float LOG2E = 1.4426950408889634f;
constexpr float NEG_HALF_LOG2E = -0.72134752044448170f;
constexpr float OUT_SCALE = -0.05f / 16384.0f; // 0.1 * -0.5 / (N*P)

typedef _Float16 half2_t __attribute__((ext_vector_type(2)));

#if __has_builtin(__builtin_amdgcn_fdot2)
#define FDOT2(a, b, c) __builtin_amdgcn_fdot2((a), (b), (c), false)
#else
static __device__ __forceinline__ float FDOT2(half2_t a, half2_t b, float c) {
  return c + (float)a.x * (float)b.x + (float)a.y * (float)b.y;
}
#endif

// Record layout (20 floats): [0..10] seg_m as half2 pairs (k=2j,2j+1; last hi=0),
// [11..15] f0..f4 (f32), [16] cs = -0.5*log2e*|f|^2, [17] gate, [18..19] pad.

__global__ void __launch_bounds__(256) prep_kernel(
    const float* __restrict__ img, const float* __restrict__ seg,
    const float* __restrict__ roi, const float* __restrict__ lab,
    float* __restrict__ rec, float* __restrict__ out) {
  int idx = blockIdx.x * 256 + threadIdx.x; // n*P + p
  if (blockIdx.x == 0 && threadIdx.x == 0) out[0] = 0.0f; // energy runs after prep
  int n = idx >> 12;
  int p = idx & (P_ - 1);
  int y = p >> 6, x = p & 63;
  int iy = 2 * y, ix = 2 * x;
  const size_t hw = (size_t)H_ * W_;

  float r = roi[(size_t)n * hw + iy * W_ + ix];
  float lb = lab[(size_t)n * hw + iy * W_ + ix];
  bool unlabeled = ((int)lb == 255);

  const float* sb = seg + (size_t)n * K_ * hw + (size_t)iy * W_ + ix;
  float sm[22];
  float mx = -1e30f;
#pragma unroll
  for (int k = 0; k < K_; k++) {
    const float* s = sb + (size_t)k * hw;
    float v = 0.25f * (s[0] + s[1] + s[W_] + s[W_ + 1]); // bilinear @0.5 == 2x2 avg
    mx = fmaxf(mx, v);
    sm[k] = v * r; // seg_m = seg_s * roi
  }
  sm[21] = 0.0f;

  float o[REC];
#pragma unroll
  for (int j = 0; j < 11; j++) {
    half2_t h;
    h.x = (_Float16)sm[2 * j];
    h.y = (_Float16)sm[2 * j + 1];
    o[j] = __builtin_bit_cast(float, h);
  }
  float f0 = (float)x * INV_XY;
  float f1 = (float)y * INV_XY;
  const float* ib = img + (size_t)n * 3 * hw + (size_t)iy * W_ + ix;
  float f2 = ib[0] * INV_RGB;
  float f3 = ib[hw] * INV_RGB;
  float f4 = ib[2 * hw] * INV_RGB;
  o[11] = f0; o[12] = f1; o[13] = f2; o[14] = f3; o[15] = f4;
  float sq = f0 * f0;
  sq = fmaf(f1, f1, sq); sq = fmaf(f2, f2, sq);
  sq = fmaf(f3, f3, sq); sq = fmaf(f4, f4, sq);
  o[16] = NEG_HALF_LOG2E * sq;
  float g = unlabeled ? 1.0f : (r - mx);
  o[17] = fmaxf(g, 0.0f);
  o[18] = 0.0f; o[19] = 0.0f;

  float4* dst = (float4*)(rec + (size_t)idx * REC);
  const float4* srcv = (const float4*)o;
#pragma unroll
  for (int j = 0; j < REC / 4; j++) dst[j] = srcv[j];
}

__global__ void __launch_bounds__(256) energy_kernel(
    const float* __restrict__ rec, float* __restrict__ out) {
  __shared__ float sh[T_ * REC]; // 10 KB, shared by all 4 waves

  // Decode upper-triangular tile pair (pb <= qb) from blockIdx.x in [0, 528).
  int t = blockIdx.x;
  int pb = 0;
  while (t >= NT - pb) { t -= NT - pb; pb++; }
  int qb = pb + t;
  int n = blockIdx.y;
  int tid = threadIdx.x;
  int lane = tid & 63, wave = tid >> 6;

  const float* base = rec + (size_t)n * P_ * REC;

  // Stage q-tile (128 records x 80 B = 640 float4) with all 256 threads.
  const float4* src = (const float4*)(base + (size_t)qb * T_ * REC);
  float4* dst = (float4*)sh;
  for (int i = tid; i < T_ * REC / 4; i += 256) dst[i] = src[i];

  // Each wave covers all 128 p's (MP=2 per lane) x its own 32-q strip.
  half2_t sp[2][11];
  float fp[2][5], csp[2], gp[2];
#pragma unroll
  for (int i = 0; i < 2; i++) {
    const float4* rp4 = (const float4*)(base + (size_t)(pb * T_ + lane + i * 64) * REC);
    float4 b0 = rp4[0], b1 = rp4[1], b2 = rp4[2], b3 = rp4[3], b4 = rp4[4];
    sp[i][0] = __builtin_bit_cast(half2_t, b0.x);
    sp[i][1] = __builtin_bit_cast(half2_t, b0.y);
    sp[i][2] = __builtin_bit_cast(half2_t, b0.z);
    sp[i][3] = __builtin_bit_cast(half2_t, b0.w);
    sp[i][4] = __builtin_bit_cast(half2_t, b1.x);
    sp[i][5] = __builtin_bit_cast(half2_t, b1.y);
    sp[i][6] = __builtin_bit_cast(half2_t, b1.z);
    sp[i][7] = __builtin_bit_cast(half2_t, b1.w);
    sp[i][8] = __builtin_bit_cast(half2_t, b2.x);
    sp[i][9] = __builtin_bit_cast(half2_t, b2.y);
    sp[i][10] = __builtin_bit_cast(half2_t, b2.z);
    fp[i][0] = b2.w;
    fp[i][1] = b3.x; fp[i][2] = b3.y; fp[i][3] = b3.z; fp[i][4] = b3.w;
    csp[i] = b4.x; gp[i] = b4.y;
  }
  __syncthreads();

  float acc = 0.0f;
  const int q0i = wave * 32;
#pragma unroll 2
  for (int qj = 0; qj < 32; qj++) {
    const float4* rq4 = (const float4*)(sh + (q0i + qj) * REC);
    float4 a0 = rq4[0], a1 = rq4[1], a2 = rq4[2], a3 = rq4[3], a4 = rq4[4];
    half2_t q0 = __builtin_bit_cast(half2_t, a0.x);
    half2_t q1 = __builtin_bit_cast(half2_t, a0.y);
    half2_t q2 = __builtin_bit_cast(half2_t, a0.z);
    half2_t q3 = __builtin_bit_cast(half2_t, a0.w);
    half2_t q4 = __builtin_bit_cast(half2_t, a1.x);
    half2_t q5 = __builtin_bit_cast(half2_t, a1.y);
    half2_t q6 = __builtin_bit_cast(half2_t, a1.z);
    half2_t q7 = __builtin_bit_cast(half2_t, a1.w);
    half2_t q8 = __builtin_bit_cast(half2_t, a2.x);
    half2_t q9 = __builtin_bit_cast(half2_t, a2.y);
    half2_t q10 = __builtin_bit_cast(half2_t, a2.z);
    float f0q = a2.w, f1q = a3.x, f2q = a3.y, f3q = a3.z, f4q = a3.w;
    float csq = a4.x, gq = a4.y;
#pragma unroll
    for (int i = 0; i < 2; i++) {
      // K-contraction: 11 half2 dot2s, two accumulators for ILP.
      float Ga = FDOT2(sp[i][0], q0, 0.0f);
      float Gb = FDOT2(sp[i][1], q1, 0.0f);
      Ga = FDOT2(sp[i][2], q2, Ga);
      Gb = FDOT2(sp[i][3], q3, Gb);
      Ga = FDOT2(sp[i][4], q4, Ga);
      Gb = FDOT2(sp[i][5], q5, Gb);
      Ga = FDOT2(sp[i][6], q6, Ga);
      Gb = FDOT2(sp[i][7], q7, Gb);
      Ga = FDOT2(sp[i][8], q8, Ga);
      Gb = FDOT2(sp[i][9], q9, Gb);
      Ga = FDOT2(sp[i][10], q10, Ga);
      // 5-dim feature dot (fp32).
      float dot = fp[i][0] * f0q;
      dot = fmaf(fp[i][1], f1q, dot);
      dot = fmaf(fp[i][2], f2q, dot);
      dot = fmaf(fp[i][3], f3q, dot);
      dot = fmaf(fp[i][4], f4q, dot);
      // A = exp(-0.5*max(d2,0)) = min(exp2(cs_p+cs_q+log2e*dot), 1)
      float arg = fmaf(LOG2E, dot, csp[i] + csq);
      float A = __builtin_amdgcn_exp2f(arg);
      A = fminf(A, 1.0f);
      acc = fmaf(A * (Ga + Gb), gp[i] + gq, acc);
    }
  }

  // Reduce: wave shuffle, then cross-wave via LDS, one atomic per block.
#pragma unroll
  for (int off = 32; off > 0; off >>= 1) acc += __shfl_down(acc, off, 64);
  __shared__ float wsum[4];
  if (lane == 0) wsum[wave] = acc;
  __syncthreads();
  if (tid == 0) {
    float s = (wsum[0] + wsum[1]) + (wsum[2] + wsum[3]);
    float wb = (pb == qb) ? 0.5f : 1.0f; // symmetrized-gate 1/2 folded with off-diag x2
    atomicAdd(out, s * wb * OUT_SCALE);
  }
}

extern "C" void kernel_launch(void* const* d_in, const int* in_sizes, int n_in,
                              void* d_out, int out_size, void* d_ws, size_t ws_size,
                              hipStream_t stream) {
  const float* images = (const float*)d_in[0];
  const float* segs = (const float*)d_in[1];
  const float* rois = (const float*)d_in[2];
  const float* labels = (const float*)d_in[3];
  float* out = (float*)d_out;
  float* rec = (float*)d_ws; // N*P*REC*4 = 1.31 MB

  prep_kernel<<<dim3(N_ * P_ / 256), dim3(256), 0, stream>>>(images, segs, rois, labels, rec, out);
  energy_kernel<<<dim3(NTRI, N_), dim3(256), 0, stream>>>(rec, out);
}